// Round 6
// baseline (362.901 us; speedup 1.0000x reference)
//
#include <hip/hip_runtime.h>
#include <hip/hip_bf16.h>
#include <cstddef>
#include <cstdint>

// Problem dims (fixed): B=512, T=64, D=128, H=128, FA=64
#define DEVI __device__ __forceinline__

typedef float f32x4 __attribute__((ext_vector_type(4)));
typedef __bf16 bf16x8 __attribute__((ext_vector_type(8)));

DEVI float fast_rcp(float x) { return __builtin_amdgcn_rcpf(x); }
DEVI float sigmoid_fast(float x) { return fast_rcp(1.0f + __expf(-x)); }
DEVI float tanh_fast(float x) { return 1.0f - 2.0f * fast_rcp(__expf(2.0f * x) + 1.0f); }
DEVI float4 ld4(const float* p) { return *reinterpret_cast<const float4*>(p); }
DEVI void st4(float* p, float4 v) { *reinterpret_cast<float4*>(p) = v; }
DEVI float f4c(const float4& v, int i) { return i == 0 ? v.x : i == 1 ? v.y : i == 2 ? v.z : v.w; }
DEVI unsigned short bfbits(float f) { return __builtin_bit_cast(unsigned short, (__bf16)f); }
DEVI unsigned pack2(float a, float b) {
  return (unsigned)bfbits(a) | ((unsigned)bfbits(b) << 16);
}
DEVI f32x4 cvt4(uint2 u) {  // 4 bf16 -> 4 f32 (shift-left-16)
  f32x4 r;
  r[0] = __builtin_bit_cast(float, (u.x & 0xffffu) << 16);
  r[1] = __builtin_bit_cast(float, u.x & 0xffff0000u);
  r[2] = __builtin_bit_cast(float, (u.y & 0xffffu) << 16);
  r[3] = __builtin_bit_cast(float, u.y & 0xffff0000u);
  return r;
}
// Barrier WITHOUT the vmcnt(0) drain __syncthreads would emit: only LDS ops
// must be visible across it; global loads/stores stay in flight (T4 principle).
DEVI void barrier_lgkm() {
  __builtin_amdgcn_sched_barrier(0);
  asm volatile("s_waitcnt lgkmcnt(0)" ::: "memory");
  __builtin_amdgcn_s_barrier();
  __builtin_amdgcn_sched_barrier(0);
}

// ---------------------------------------------------------------------------
// K1: attribute attention -> alpha_attri[128]. One block, 128 threads.
// ---------------------------------------------------------------------------
__global__ __launch_bounds__(128) void k_alpha(
    const float* __restrict__ AD, const float* __restrict__ W1,
    const float* __restrict__ B1, const float* __restrict__ W2,
    const float* __restrict__ B2, float* __restrict__ alpha) {
  __shared__ float sW1[64 * 32];
  __shared__ float sW2[32];
  __shared__ float sB1[32];
  __shared__ float red[128];
  __shared__ float s_mx, s_sum;
  int tid = threadIdx.x;
  for (int i = tid; i < 64 * 32; i += 128) sW1[i] = W1[i];
  if (tid < 32) { sW2[tid] = W2[tid]; sB1[tid] = B1[tid]; }
  __syncthreads();
  float ad[64];
  #pragma unroll
  for (int f = 0; f < 64; ++f) ad[f] = AD[tid * 64 + f];
  float logit = B2[0];
  #pragma unroll
  for (int j = 0; j < 32; ++j) {
    float a = sB1[j];
    #pragma unroll
    for (int f = 0; f < 64; ++f) a = fmaf(ad[f], sW1[f * 32 + j], a);
    a = a > 0.0f ? a : 0.5f * a;  // LeakyReLU(0.5)
    logit = fmaf(a, sW2[j], logit);
  }
  red[tid] = logit;
  __syncthreads();
  if (tid == 0) {
    float mx = red[0];
    for (int i = 1; i < 128; ++i) mx = fmaxf(mx, red[i]);
    float sm = 0.0f;
    for (int i = 0; i < 128; ++i) sm += __expf(red[i] - mx);
    s_mx = mx; s_sum = sm;
  }
  __syncthreads();
  alpha[tid] = __expf(logit - s_mx) / s_sum;
}

// ---------------------------------------------------------------------------
// K1b: wA[j][d] = bf16(w_ih[j][d] * alpha[d]); biasJ[j] = b_ih[j]+b_hh[j].
// 64 blocks x 256 threads.
// ---------------------------------------------------------------------------
__global__ __launch_bounds__(256) void k_wih(
    const float* __restrict__ w_ih, const float* __restrict__ alpha,
    const float* __restrict__ b_ih, const float* __restrict__ b_hh,
    __hip_bfloat16* __restrict__ wA, float* __restrict__ biasJ) {
  int i4 = blockIdx.x * 256 + threadIdx.x;   // 16384 quads
  int j = i4 >> 5, d0 = (i4 & 31) * 4;
  float4 w = ld4(&w_ih[(size_t)j * 128 + d0]);
  float4 a = ld4(&alpha[d0]);
  uint2 o;
  o.x = pack2(w.x * a.x, w.y * a.y);
  o.y = pack2(w.z * a.z, w.w * a.w);
  *reinterpret_cast<uint2*>(&wA[(size_t)j * 128 + d0]) = o;
  if (i4 < 128) {
    int jb = i4 * 4;
    float4 v0 = ld4(&b_ih[jb]), v1 = ld4(&b_hh[jb]);
    v0.x += v1.x; v0.y += v1.y; v0.z += v1.z; v0.w += v1.w;
    st4(&biasJ[jb], v0);
  }
}

// ---------------------------------------------------------------------------
// K1c: transpose w_a1[0:256][128] fp32 -> w1T[128 n][256 m] bf16.
// ---------------------------------------------------------------------------
__global__ __launch_bounds__(256) void k_tw(
    const float* __restrict__ w_a1, __hip_bfloat16* __restrict__ w1T) {
  __shared__ float tile[64][132];
  int blk = blockIdx.x;
  int tid = threadIdx.x;
  #pragma unroll
  for (int i = 0; i < 32; ++i) {
    int idx = i * 256 + tid;
    int r = idx >> 7, c = idx & 127;
    tile[r][c] = w_a1[(size_t)(blk * 64 + r) * 128 + c];
  }
  __syncthreads();
  int n = tid >> 1, mh = tid & 1;
  unsigned* dst = reinterpret_cast<unsigned*>(&w1T[(size_t)n * 256 + blk * 64 + mh * 32]);
  #pragma unroll
  for (int i = 0; i < 16; ++i) {
    float a = tile[mh * 32 + 2 * i][n];
    float b = tile[mh * 32 + 2 * i + 1][n];
    dst[i] = pack2(a, b);
  }
}

// ---------------------------------------------------------------------------
// K2: EP[b,d,k] = exp(clamp(2*(alpha[d]*sum_tau X[b,tau,d]*w_a1[256+tau,k] + b_a1[k])))
// One block per b. 256 threads, outputs 128x128.
// ---------------------------------------------------------------------------
__global__ __launch_bounds__(256) void k_ep(
    const float* __restrict__ X, const float* __restrict__ w_a1,
    const float* __restrict__ b_a1, const float* __restrict__ alpha,
    float* __restrict__ EP) {
  __shared__ float Xb[64][128];
  __shared__ float Wx[64][128];
  int b = blockIdx.x;
  int tid = threadIdx.x;
  #pragma unroll
  for (int i = 0; i < 8; ++i) {
    int l4 = i * 256 + tid;
    int r = l4 >> 5, c4 = l4 & 31;
    st4(&Xb[r][c4 * 4], ld4(&X[((size_t)b * 64 + r) * 128 + c4 * 4]));
    st4(&Wx[r][c4 * 4], ld4(&w_a1[(size_t)(256 + r) * 128 + c4 * 4]));
  }
  __syncthreads();
  int dg = tid & 15, kg = tid >> 4;
  float acc[8][8] = {};
  #pragma unroll 4
  for (int tau = 0; tau < 64; ++tau) {
    float4 xa0 = ld4(&Xb[tau][dg * 4]);
    float4 xa1 = ld4(&Xb[tau][64 + dg * 4]);
    float4 wa0 = ld4(&Wx[tau][kg * 4]);
    float4 wa1 = ld4(&Wx[tau][64 + kg * 4]);
    #pragma unroll
    for (int i = 0; i < 8; ++i) {
      float xv = (i < 4) ? f4c(xa0, i) : f4c(xa1, i - 4);
      #pragma unroll
      for (int j = 0; j < 4; ++j) {
        acc[i][j]     = fmaf(xv, f4c(wa0, j), acc[i][j]);
        acc[i][j + 4] = fmaf(xv, f4c(wa1, j), acc[i][j + 4]);
      }
    }
  }
  float4 ba0 = ld4(&b_a1[kg * 4]);
  float4 ba1v = ld4(&b_a1[64 + kg * 4]);
  #pragma unroll
  for (int i = 0; i < 8; ++i) {
    int drow = (i < 4) ? dg * 4 + i : 64 + dg * 4 + (i - 4);
    float al = alpha[drow];
    float4 o0, o1;
    float* p0 = &o0.x; float* p1 = &o1.x;
    #pragma unroll
    for (int j = 0; j < 4; ++j) {
      float v0 = 2.0f * fmaf(al, acc[i][j],     f4c(ba0, j));
      float v1 = 2.0f * fmaf(al, acc[i][j + 4], f4c(ba1v, j));
      p0[j] = __expf(fminf(fmaxf(v0, -40.0f), 40.0f));
      p1[j] = __expf(fminf(fmaxf(v1, -40.0f), 40.0f));
    }
    st4(&EP[((size_t)b * 128 + drow) * 128 + kg * 4], o0);
    st4(&EP[((size_t)b * 128 + drow) * 128 + 64 + kg * 4], o1);
  }
}

// ---------------------------------------------------------------------------
// K2b: gx[r=(b*64+t)][j] bf16 = sum_d X[r][d]*wA[j][d] + biasJ[j]
// bf16 MFMA; grid (256 rt, 4 jt) so jt-mates are 256 apart -> same XCD/L2.
// Block: 128 rows x 128 j; 4 waves, each wave 32 j x 128 rows.
// ---------------------------------------------------------------------------
__global__ __launch_bounds__(256, 2) void k_gxw(
    const float* __restrict__ X, const __hip_bfloat16* __restrict__ wA,
    const float* __restrict__ biasJ, __hip_bfloat16* __restrict__ gx) {
  int rt = blockIdx.x, jt = blockIdx.y;
  int tid = threadIdx.x;
  int wv = tid >> 6, l = tid & 63, lg = l >> 4, lr = l & 15;
  int r0 = rt * 128;
  int j0 = jt * 128 + wv * 32;

  // A-frags (wA rows = j): a[ri][ks], row = j0 + ri*16 + lr, k(d) = ks*32+lg*8
  bf16x8 a[2][4];
  #pragma unroll
  for (int ri = 0; ri < 2; ++ri)
    #pragma unroll
    for (int ks = 0; ks < 4; ++ks)
      a[ri][ks] = *reinterpret_cast<const bf16x8*>(
          &wA[(size_t)(j0 + ri * 16 + lr) * 128 + ks * 32 + lg * 8]);

  f32x4 acc[2][8];
  #pragma unroll
  for (int ri = 0; ri < 2; ++ri)
    #pragma unroll
    for (int nj = 0; nj < 8; ++nj) acc[ri][nj] = (f32x4){0.f, 0.f, 0.f, 0.f};

  #pragma unroll 2
  for (int nj = 0; nj < 8; ++nj) {
    // B-frags (X rows = output rows): n = lr, k(d) = ks*32+lg*8
    bf16x8 bh[4];
    #pragma unroll
    for (int ks = 0; ks < 4; ++ks) {
      const float* src = &X[(size_t)(r0 + nj * 16 + lr) * 128 + ks * 32 + lg * 8];
      float4 f0 = ld4(src), f1 = ld4(src + 4);
      bf16x8 fr;
      fr[0] = (__bf16)f0.x; fr[1] = (__bf16)f0.y;
      fr[2] = (__bf16)f0.z; fr[3] = (__bf16)f0.w;
      fr[4] = (__bf16)f1.x; fr[5] = (__bf16)f1.y;
      fr[6] = (__bf16)f1.z; fr[7] = (__bf16)f1.w;
      bh[ks] = fr;
    }
    #pragma unroll
    for (int ks = 0; ks < 4; ++ks) {
      acc[0][nj] = __builtin_amdgcn_mfma_f32_16x16x32_bf16(a[0][ks], bh[ks], acc[0][nj], 0, 0, 0);
      acc[1][nj] = __builtin_amdgcn_mfma_f32_16x16x32_bf16(a[1][ks], bh[ks], acc[1][nj], 0, 0, 0);
    }
  }

  // C: row(j) = j0 + ri*16 + lg*4 + reg, col(r) = r0 + nj*16 + lr
  #pragma unroll
  for (int ri = 0; ri < 2; ++ri) {
    int jb = j0 + ri * 16 + lg * 4;
    float4 bi = ld4(&biasJ[jb]);
    #pragma unroll
    for (int nj = 0; nj < 8; ++nj) {
      int row = r0 + nj * 16 + lr;
      uint2 o;
      o.x = pack2(acc[ri][nj][0] + bi.x, acc[ri][nj][1] + bi.y);
      o.y = pack2(acc[ri][nj][2] + bi.z, acc[ri][nj][3] + bi.w);
      *reinterpret_cast<uint2*>(&gx[(size_t)row * 512 + jb]) = o;
    }
  }
}

// ---------------------------------------------------------------------------
// K3: LSTM recurrence, h-path only (gx precomputed, bias folded).
// 32 blocks x 512 threads; block owns 16 batches. Per step:
//   gates[512j x 16b] = w_hh(bf16 A-frags, 64 VGPR) @ h(bf16, LDS) + gx(t)
// gx(t) prefetched 2 steps ahead as MFMA C-init; lgkm-only barrier keeps
// S stores + gx loads in flight. LDS 2 x 4KB, XOR-granule swizzled (2-way=free).
// ---------------------------------------------------------------------------
__global__ __launch_bounds__(512, 1) void k_rec(
    const __hip_bfloat16* __restrict__ gx, const float* __restrict__ w_hh,
    __hip_bfloat16* __restrict__ S) {
  __shared__ unsigned short kB[2][16 * 128];  // [batch-row lr][m], swizzled
  int tid = threadIdx.x;
  int wv = tid >> 6, l = tid & 63, lg = l >> 4, lr = l & 15;
  int b0 = blockIdx.x * 16;

  // A-frags: ah[ks][q]; j = q*128 + wv*16 + lr; k(m) = ks*32 + lg*8 + e
  bf16x8 ah[4][4];
  #pragma unroll
  for (int ks = 0; ks < 4; ++ks)
    #pragma unroll
    for (int q = 0; q < 4; ++q) {
      const float* src = &w_hh[(size_t)(q * 128 + wv * 16 + lr) * 128 + ks * 32 + lg * 8];
      float4 f0 = ld4(src), f1 = ld4(src + 4);
      bf16x8 fr;
      fr[0] = (__bf16)f0.x; fr[1] = (__bf16)f0.y;
      fr[2] = (__bf16)f0.z; fr[3] = (__bf16)f0.w;
      fr[4] = (__bf16)f1.x; fr[5] = (__bf16)f1.y;
      fr[6] = (__bf16)f1.z; fr[7] = (__bf16)f1.w;
      ah[ks][q] = fr;
    }

  alignas(16) float hA[4] = {0.f, 0.f, 0.f, 0.f};
  alignas(16) float cA[4] = {0.f, 0.f, 0.f, 0.f};
  int m0 = wv * 16 + lg * 4;
  int wIdx = lr * 128 + (((m0 >> 3) ^ lr) << 3) + (m0 & 7);  // swizzled write slot
  const __hip_bfloat16* gxb = gx + (size_t)(b0 + lr) * 64 * 512 + wv * 16 + lg * 4;

  // prologue: h(0)=0; prefetch gx(0), gx(1)
  uint2 z; z.x = 0u; z.y = 0u;
  *reinterpret_cast<uint2*>(&kB[0][wIdx]) = z;
  uint2 gA[4], gB[4];
  #pragma unroll
  for (int q = 0; q < 4; ++q) gA[q] = *reinterpret_cast<const uint2*>(gxb + q * 128);
  #pragma unroll
  for (int q = 0; q < 4; ++q) gB[q] = *reinterpret_cast<const uint2*>(gxb + 512 + q * 128);
  __syncthreads();

#define REC_STEP(T, SRC, DST, G)                                               \
  do {                                                                         \
    int t_ = (T);                                                              \
    bf16x8 bh[4];                                                              \
    _Pragma("unroll")                                                          \
    for (int ks = 0; ks < 4; ++ks)                                             \
      bh[ks] = *reinterpret_cast<const bf16x8*>(                               \
          &kB[SRC][lr * 128 + ((((ks << 2) + lg) ^ lr) << 3)]);                \
    f32x4 ac0 = cvt4(G[0]), ac1 = cvt4(G[1]), ac2 = cvt4(G[2]), ac3 = cvt4(G[3]); \
    int tn_ = t_ + 2 < 64 ? t_ + 2 : 63;                                       \
    _Pragma("unroll")                                                          \
    for (int q = 0; q < 4; ++q)                                                \
      G[q] = *reinterpret_cast<const uint2*>(gxb + (size_t)tn_ * 512 + q * 128); \
    {                                                                          \
      uint2 hS; hS.x = pack2(hA[0], hA[1]); hS.y = pack2(hA[2], hA[3]);        \
      uint2 cS; cS.x = pack2(cA[0], cA[1]); cS.y = pack2(cA[2], cA[3]);        \
      __hip_bfloat16* sp = S + ((size_t)(t_ * 512) + b0 + lr) * 256 + m0;      \
      *reinterpret_cast<uint2*>(sp) = hS;                                      \
      *reinterpret_cast<uint2*>(sp + 128) = cS;                                \
    }                                                                          \
    _Pragma("unroll")                                                          \
    for (int ks = 0; ks < 4; ++ks) {                                           \
      ac0 = __builtin_amdgcn_mfma_f32_16x16x32_bf16(ah[ks][0], bh[ks], ac0, 0, 0, 0); \
      ac1 = __builtin_amdgcn_mfma_f32_16x16x32_bf16(ah[ks][1], bh[ks], ac1, 0, 0, 0); \
      ac2 = __builtin_amdgcn_mfma_f32_16x16x32_bf16(ah[ks][2], bh[ks], ac2, 0, 0, 0); \
      ac3 = __builtin_amdgcn_mfma_f32_16x16x32_bf16(ah[ks][3], bh[ks], ac3, 0, 0, 0); \
    }                                                                          \
    _Pragma("unroll")                                                          \
    for (int r = 0; r < 4; ++r) {                                              \
      float ig = sigmoid_fast(ac0[r]);                                         \
      float fg = sigmoid_fast(ac1[r]);                                         \
      float gg = tanh_fast(ac2[r]);                                            \
      float og = sigmoid_fast(ac3[r]);                                         \
      float cn = fmaf(fg, cA[r], ig * gg);                                     \
      float hn = og * tanh_fast(cn);                                           \
      cA[r] = cn; hA[r] = hn;                                                  \
    }                                                                          \
    {                                                                          \
      uint2 hu; hu.x = pack2(hA[0], hA[1]); hu.y = pack2(hA[2], hA[3]);        \
      *reinterpret_cast<uint2*>(&kB[DST][wIdx]) = hu;                          \
    }                                                                          \
    barrier_lgkm();                                                            \
  } while (0)

  #pragma unroll 1
  for (int it = 0; it < 32; ++it) {
    REC_STEP(2 * it, 0, 1, gA);
    REC_STEP(2 * it + 1, 1, 0, gB);
  }
#undef REC_STEP
}

// ---------------------------------------------------------------------------
// K4: EQ[t*512+b, n] = exp(clamp(2 * sum_{m<256} S[t*512+b, m]*w1T[n, m]))
// bf16 MFMA, register-only: 256 blocks x 256 thr, wave = 32 rows.
// ---------------------------------------------------------------------------
__global__ __launch_bounds__(256, 1) void k_eq(
    const __hip_bfloat16* __restrict__ S, const __hip_bfloat16* __restrict__ w1T,
    float* __restrict__ EQ) {
  int tid = threadIdx.x;
  int wv = tid >> 6, l = tid & 63;
  int lr = l & 15, lg = l >> 4;
  int r0 = blockIdx.x * 128 + wv * 32;

  bf16x8 a[2][8];
  #pragma unroll
  for (int ri = 0; ri < 2; ++ri)
    #pragma unroll
    for (int ks = 0; ks < 8; ++ks)
      a[ri][ks] = *reinterpret_cast<const bf16x8*>(
          &S[(size_t)(r0 + ri * 16 + lr) * 256 + ks * 32 + lg * 8]);

  f32x4 acc[2][8];
  #pragma unroll
  for (int ri = 0; ri < 2; ++ri)
    #pragma unroll
    for (int nj = 0; nj < 8; ++nj) acc[ri][nj] = (f32x4){0.f, 0.f, 0.f, 0.f};

  #pragma unroll
  for (int nj = 0; nj < 8; ++nj) {
    bf16x8 bf[8];
    #pragma unroll
    for (int ks = 0; ks < 8; ++ks)
      bf[ks] = *reinterpret_cast<const bf16x8*>(
          &w1T[(size_t)(nj * 16 + lr) * 256 + ks * 32 + lg * 8]);
    #pragma unroll
    for (int ks = 0; ks < 8; ++ks) {
      acc[0][nj] = __builtin_amdgcn_mfma_f32_16x16x32_bf16(a[0][ks], bf[ks], acc[0][nj], 0, 0, 0);
      acc[1][nj] = __builtin_amdgcn_mfma_f32_16x16x32_bf16(a[1][ks], bf[ks], acc[1][nj], 0, 0, 0);
    }
  }

  #pragma unroll
  for (int ri = 0; ri < 2; ++ri)
    #pragma unroll
    for (int nj = 0; nj < 8; ++nj)
      #pragma unroll
      for (int r = 0; r < 4; ++r) {
        int grow = r0 + ri * 16 + lg * 4 + r;
        int n = nj * 16 + lr;
        float v = 2.0f * acc[ri][nj][r];
        EQ[(size_t)grow * 128 + n] = __expf(fminf(fmaxf(v, -40.f), 40.f));
      }
}

// ---------------------------------------------------------------------------
// K5: per (b): e'[t,d] = -2*sum_k w_a2[k]*rcp(EP[b,d,k]*EQ[t,b,k]+1);
// softmax over d; out[b,t,d] = sm * alpha[d] * X[b,t,d].
// 8 t's per barrier round; lgkm-only barriers (out-stores stay in flight).
// ---------------------------------------------------------------------------
__global__ __launch_bounds__(512, 2) void k_attn(
    const float* __restrict__ EP, const float* __restrict__ EQ,
    const float* __restrict__ w_a2, const float* __restrict__ alpha,
    const float* __restrict__ X, float* __restrict__ out) {
  __shared__ float EQs[64][128];
  __shared__ float e_lds[8][128];
  int b = blockIdx.x;
  int tid = threadIdx.x;
  #pragma unroll
  for (int i = 0; i < 4; ++i) {
    int l4 = i * 512 + tid;
    int t = l4 >> 5, k4 = l4 & 31;
    st4(&EQs[t][k4 * 4], ld4(&EQ[((size_t)t * 512 + b) * 128 + k4 * 4]));
  }
  int d = tid >> 2, s = tid & 3;
  float4 ep[8], w2r[8];
  #pragma unroll
  for (int q = 0; q < 8; ++q) {
    ep[q]  = ld4(&EP[((size_t)b * 128 + d) * 128 + s * 32 + q * 4]);
    w2r[q] = ld4(&w_a2[s * 32 + q * 4]);
  }
  int wv = tid >> 6, l = tid & 63;
  float al0 = alpha[l], al1 = alpha[64 + l];
  barrier_lgkm();

  for (int rnd = 0; rnd < 8; ++rnd) {
    #pragma unroll
    for (int it = 0; it < 8; ++it) {
      int t = rnd * 8 + it;
      float p = 0.0f;
      #pragma unroll
      for (int q = 0; q < 8; ++q) {
        float4 eq = ld4(&EQs[t][s * 32 + q * 4]);
        p = fmaf(w2r[q].x, fast_rcp(fmaf(ep[q].x, eq.x, 1.0f)), p);
        p = fmaf(w2r[q].y, fast_rcp(fmaf(ep[q].y, eq.y, 1.0f)), p);
        p = fmaf(w2r[q].z, fast_rcp(fmaf(ep[q].z, eq.z, 1.0f)), p);
        p = fmaf(w2r[q].w, fast_rcp(fmaf(ep[q].w, eq.w, 1.0f)), p);
      }
      p += __shfl_xor(p, 1);
      p += __shfl_xor(p, 2);
      if (s == 0) e_lds[it][d] = -2.0f * p;
    }
    barrier_lgkm();
    {
      int t = rnd * 8 + wv;
      float v0 = e_lds[wv][l], v1 = e_lds[wv][64 + l];
      float mx = fmaxf(v0, v1);
      #pragma unroll
      for (int o = 1; o < 64; o <<= 1) mx = fmaxf(mx, __shfl_xor(mx, o));
      float e0 = __expf(v0 - mx), e1 = __expf(v1 - mx);
      float sm = e0 + e1;
      #pragma unroll
      for (int o = 1; o < 64; o <<= 1) sm += __shfl_xor(sm, o);
      float inv = fast_rcp(sm);
      size_t ro = ((size_t)b * 64 + t) * 128;
      out[ro + l]      = e0 * inv * al0 * X[ro + l];
      out[ro + 64 + l] = e1 * inv * al1 * X[ro + 64 + l];
    }
    barrier_lgkm();
  }
}

// ---------------------------------------------------------------------------
extern "C" void kernel_launch(void* const* d_in, const int* in_sizes, int n_in,
                              void* d_out, int out_size, void* d_ws, size_t ws_size,
                              hipStream_t stream) {
  const float* X    = (const float*)d_in[0];
  const float* AD   = (const float*)d_in[1];
  const float* W1   = (const float*)d_in[2];
  const float* B1   = (const float*)d_in[3];
  const float* W2   = (const float*)d_in[4];
  const float* B2   = (const float*)d_in[5];
  const float* w_a1 = (const float*)d_in[6];
  const float* b_a1 = (const float*)d_in[7];
  const float* w_a2 = (const float*)d_in[8];
  // d_in[9] = b_a2: softmax-invariant, unused
  const float* w_ih = (const float*)d_in[10];
  const float* w_hh = (const float*)d_in[11];
  const float* b_ih = (const float*)d_in[12];
  const float* b_hh = (const float*)d_in[13];
  float* out = (float*)d_out;
  float* ws = (float*)d_ws;

  // workspace layout (float units)
  float* alpha = ws;                                    // 256
  float* EQ    = ws + 256;                              // 4194304
  float* EP    = EQ + 4194304;                          // 8388608
  float* fS    = EP + 8388608;                          // S bf16: 4194304 floats
  __hip_bfloat16* S = (__hip_bfloat16*)fS;
  float* fgx   = fS + 4194304;                          // gx bf16: 8388608 floats
  __hip_bfloat16* gx = (__hip_bfloat16*)fgx;
  float* fw1T  = fgx + 8388608;                         // w1T bf16: 16384 floats
  __hip_bfloat16* w1T = (__hip_bfloat16*)fw1T;
  float* fwA   = fw1T + 16384;                          // wA bf16: 32768 floats
  __hip_bfloat16* wA = (__hip_bfloat16*)fwA;
  float* biasJ = fwA + 32768;                           // 512
  // total ~= 25.2M floats ~= 101 MB

  hipLaunchKernelGGL(k_alpha, dim3(1),   dim3(128), 0, stream, AD, W1, B1, W2, B2, alpha);
  hipLaunchKernelGGL(k_wih,   dim3(64),  dim3(256), 0, stream, w_ih, alpha, b_ih, b_hh, wA, biasJ);
  hipLaunchKernelGGL(k_tw,    dim3(4),   dim3(256), 0, stream, w_a1, w1T);
  hipLaunchKernelGGL(k_ep,    dim3(512), dim3(256), 0, stream, X, w_a1, b_a1, alpha, EP);
  hipLaunchKernelGGL(k_gxw,   dim3(256, 4), dim3(256), 0, stream, X, wA, biasJ, gx);
  hipLaunchKernelGGL(k_rec,   dim3(32),  dim3(512), 0, stream, gx, w_hh, S);
  hipLaunchKernelGGL(k_eq,    dim3(256), dim3(256), 0, stream, S, w1T, EQ);
  hipLaunchKernelGGL(k_attn,  dim3(512), dim3(512), 0, stream, EP, EQ, w_a2, alpha, X, out);
}

// Round 7
// 331.018 us; speedup vs baseline: 1.0963x; 1.0963x over previous
//
#include <hip/hip_runtime.h>
#include <hip/hip_bf16.h>
#include <cstddef>
#include <cstdint>

// Problem dims (fixed): B=512, T=64, D=128, H=128, FA=64
#define DEVI __device__ __forceinline__

typedef float f32x4 __attribute__((ext_vector_type(4)));
typedef __bf16 bf16x8 __attribute__((ext_vector_type(8)));

DEVI float fast_rcp(float x) { return __builtin_amdgcn_rcpf(x); }
DEVI float sigmoid_fast(float x) { return fast_rcp(1.0f + __expf(-x)); }
DEVI float tanh_fast(float x) { return 1.0f - 2.0f * fast_rcp(__expf(2.0f * x) + 1.0f); }
DEVI float4 ld4(const float* p) { return *reinterpret_cast<const float4*>(p); }
DEVI void st4(float* p, float4 v) { *reinterpret_cast<float4*>(p) = v; }
DEVI float f4c(const float4& v, int i) { return i == 0 ? v.x : i == 1 ? v.y : i == 2 ? v.z : v.w; }
DEVI unsigned short bfbits(float f) { return __builtin_bit_cast(unsigned short, (__bf16)f); }
DEVI unsigned pack2(float a, float b) {
  return (unsigned)bfbits(a) | ((unsigned)bfbits(b) << 16);
}
DEVI f32x4 cvt4(uint2 u) {  // 4 bf16 -> 4 f32 (shift-left-16)
  f32x4 r;
  r[0] = __builtin_bit_cast(float, (u.x & 0xffffu) << 16);
  r[1] = __builtin_bit_cast(float, u.x & 0xffff0000u);
  r[2] = __builtin_bit_cast(float, (u.y & 0xffffu) << 16);
  r[3] = __builtin_bit_cast(float, u.y & 0xffff0000u);
  return r;
}
// Barrier WITHOUT the vmcnt(0) drain __syncthreads would emit (global loads/
// stores stay in flight across it; only LDS ops must be visible).
DEVI void barrier_lgkm() {
  __builtin_amdgcn_sched_barrier(0);
  asm volatile("s_waitcnt lgkmcnt(0)" ::: "memory");
  __builtin_amdgcn_s_barrier();
  __builtin_amdgcn_sched_barrier(0);
}

// ---------------------------------------------------------------------------
// K_PREP: fused {alpha (redundant per wih-block), wA/biasJ, w1T transpose}.
// Blocks 0..63: alpha + wA slice (+ block 0 writes alpha_g, biasJ).
// Blocks 64..67: w_a1[0:256]^T -> w1T bf16.
// ---------------------------------------------------------------------------
__global__ __launch_bounds__(256) void k_prep(
    const float* __restrict__ AD, const float* __restrict__ W1,
    const float* __restrict__ B1, const float* __restrict__ W2,
    const float* __restrict__ B2, const float* __restrict__ w_ih,
    const float* __restrict__ b_ih, const float* __restrict__ b_hh,
    const float* __restrict__ w_a1, float* __restrict__ alpha_g,
    __hip_bfloat16* __restrict__ wA, float* __restrict__ biasJ,
    __hip_bfloat16* __restrict__ w1T) {
  __shared__ float sh[64 * 132];  // 33 KB, carved per role
  int bid = blockIdx.x, tid = threadIdx.x;
  if (bid < 64) {
    float* sW1 = sh;            // 2048
    float* sW2 = sh + 2048;     // 32
    float* sB1 = sh + 2080;     // 32
    float* red = sh + 2112;     // 128
    float* sA  = sh + 2240;     // 128
    float* sMS = sh + 2368;     // 2
    for (int i = tid; i < 2048; i += 256) sW1[i] = W1[i];
    if (tid < 32) { sW2[tid] = W2[tid]; sB1[tid] = B1[tid]; }
    __syncthreads();
    if (tid < 128) {
      float ad[64];
      #pragma unroll
      for (int f = 0; f < 64; ++f) ad[f] = AD[tid * 64 + f];
      float logit = B2[0];
      #pragma unroll
      for (int j = 0; j < 32; ++j) {
        float a = sB1[j];
        #pragma unroll
        for (int f = 0; f < 64; ++f) a = fmaf(ad[f], sW1[f * 32 + j], a);
        a = a > 0.0f ? a : 0.5f * a;  // LeakyReLU(0.5)
        logit = fmaf(a, sW2[j], logit);
      }
      red[tid] = logit;
    }
    __syncthreads();
    if (tid == 0) {
      float mx = red[0];
      for (int i = 1; i < 128; ++i) mx = fmaxf(mx, red[i]);
      float sm = 0.0f;
      for (int i = 0; i < 128; ++i) sm += __expf(red[i] - mx);
      sMS[0] = mx; sMS[1] = sm;
    }
    __syncthreads();
    if (tid < 128) {
      float a = __expf(red[tid] - sMS[0]) / sMS[1];
      sA[tid] = a;
      if (bid == 0) alpha_g[tid] = a;
    }
    __syncthreads();
    // wA slice: 256 quads per block
    int i4 = bid * 256 + tid;
    int j = i4 >> 5, d0 = (i4 & 31) * 4;
    float4 w = ld4(&w_ih[(size_t)j * 128 + d0]);
    uint2 o;
    o.x = pack2(w.x * sA[d0], w.y * sA[d0 + 1]);
    o.y = pack2(w.z * sA[d0 + 2], w.w * sA[d0 + 3]);
    *reinterpret_cast<uint2*>(&wA[(size_t)j * 128 + d0]) = o;
    if (i4 < 128) {
      int jb = i4 * 4;
      float4 v0 = ld4(&b_ih[jb]), v1 = ld4(&b_hh[jb]);
      v0.x += v1.x; v0.y += v1.y; v0.z += v1.z; v0.w += v1.w;
      st4(&biasJ[jb], v0);
    }
  } else {
    // w1T transpose role
    float (*tile)[132] = reinterpret_cast<float(*)[132]>(sh);
    int blk = bid - 64;
    #pragma unroll
    for (int i = 0; i < 32; ++i) {
      int idx = i * 256 + tid;
      int r = idx >> 7, c = idx & 127;
      tile[r][c] = w_a1[(size_t)(blk * 64 + r) * 128 + c];
    }
    __syncthreads();
    int n = tid >> 1, mh = tid & 1;
    unsigned* dst = reinterpret_cast<unsigned*>(&w1T[(size_t)n * 256 + blk * 64 + mh * 32]);
    #pragma unroll
    for (int i = 0; i < 16; ++i) {
      float a = tile[mh * 32 + 2 * i][n];
      float b = tile[mh * 32 + 2 * i + 1][n];
      dst[i] = pack2(a, b);
    }
  }
}

// ---------------------------------------------------------------------------
// K_GXW: gx[r=(b*64+t)][j] bf16 = sum_d X[r][d]*wA[j][d] + biasJ[j]
// bf16 MFMA; grid (256 rt, 4 jt). Block: 128 rows x 128 j; 4 waves.
// ---------------------------------------------------------------------------
__global__ __launch_bounds__(256, 2) void k_gxw(
    const float* __restrict__ X, const __hip_bfloat16* __restrict__ wA,
    const float* __restrict__ biasJ, __hip_bfloat16* __restrict__ gx) {
  int rt = blockIdx.x, jt = blockIdx.y;
  int tid = threadIdx.x;
  int wv = tid >> 6, l = tid & 63, lg = l >> 4, lr = l & 15;
  int r0 = rt * 128;
  int j0 = jt * 128 + wv * 32;

  bf16x8 a[2][4];
  #pragma unroll
  for (int ri = 0; ri < 2; ++ri)
    #pragma unroll
    for (int ks = 0; ks < 4; ++ks)
      a[ri][ks] = *reinterpret_cast<const bf16x8*>(
          &wA[(size_t)(j0 + ri * 16 + lr) * 128 + ks * 32 + lg * 8]);

  f32x4 acc[2][8];
  #pragma unroll
  for (int ri = 0; ri < 2; ++ri)
    #pragma unroll
    for (int nj = 0; nj < 8; ++nj) acc[ri][nj] = (f32x4){0.f, 0.f, 0.f, 0.f};

  #pragma unroll 2
  for (int nj = 0; nj < 8; ++nj) {
    bf16x8 bh[4];
    #pragma unroll
    for (int ks = 0; ks < 4; ++ks) {
      const float* src = &X[(size_t)(r0 + nj * 16 + lr) * 128 + ks * 32 + lg * 8];
      float4 f0 = ld4(src), f1 = ld4(src + 4);
      bf16x8 fr;
      fr[0] = (__bf16)f0.x; fr[1] = (__bf16)f0.y;
      fr[2] = (__bf16)f0.z; fr[3] = (__bf16)f0.w;
      fr[4] = (__bf16)f1.x; fr[5] = (__bf16)f1.y;
      fr[6] = (__bf16)f1.z; fr[7] = (__bf16)f1.w;
      bh[ks] = fr;
    }
    #pragma unroll
    for (int ks = 0; ks < 4; ++ks) {
      acc[0][nj] = __builtin_amdgcn_mfma_f32_16x16x32_bf16(a[0][ks], bh[ks], acc[0][nj], 0, 0, 0);
      acc[1][nj] = __builtin_amdgcn_mfma_f32_16x16x32_bf16(a[1][ks], bh[ks], acc[1][nj], 0, 0, 0);
    }
  }

  #pragma unroll
  for (int ri = 0; ri < 2; ++ri) {
    int jb = j0 + ri * 16 + lg * 4;
    float4 bi = ld4(&biasJ[jb]);
    #pragma unroll
    for (int nj = 0; nj < 8; ++nj) {
      int row = r0 + nj * 16 + lr;
      uint2 o;
      o.x = pack2(acc[ri][nj][0] + bi.x, acc[ri][nj][1] + bi.y);
      o.y = pack2(acc[ri][nj][2] + bi.z, acc[ri][nj][3] + bi.w);
      *reinterpret_cast<uint2*>(&gx[(size_t)row * 512 + jb]) = o;
    }
  }
}

// ---------------------------------------------------------------------------
// K_RECEP: blocks 0..31 = LSTM recurrence + fused EQ; blocks 32..543 = EP.
// The EP blocks run CONCURRENTLY on the ~224 CUs the recurrence leaves idle.
//
// Recurrence (per block: 16 batches, 512 thr):
//   gates = w_hh(A-frags, 64 VGPR) @ h(LDS bf16) + gx(t) [C-init, prefetched]
//   EQ[t,b,n] = exp(2*[h;c]@w1T[n,:]) fused: A=w1T frags (32 VGPR, loaded once),
//   B = same h-frags as gates + 4 kC reads. S never materialized.
// EP (per block: one b): EP[b,d,k] = exp(2*(alpha[d]*sum_tau X*w1 + b1))
// ---------------------------------------------------------------------------
__global__ __launch_bounds__(512, 1) void k_recep(
    const __hip_bfloat16* __restrict__ gx, const float* __restrict__ w_hh,
    const __hip_bfloat16* __restrict__ w1T, float* __restrict__ EQ,
    const float* __restrict__ X, const float* __restrict__ w_a1,
    const float* __restrict__ b_a1, const float* __restrict__ alpha_g,
    float* __restrict__ EP) {
  __shared__ float shmem[2 * 64 * 128];  // 64 KB
  int bid = blockIdx.x;
  int tid = threadIdx.x;

  if (bid >= 32) {
    // ---------------- EP role ----------------
    int b = bid - 32;
    float (*Xb)[128] = reinterpret_cast<float(*)[128]>(&shmem[0]);
    float (*Wx)[128] = reinterpret_cast<float(*)[128]>(&shmem[8192]);
    #pragma unroll
    for (int i = 0; i < 4; ++i) {
      int l4 = i * 512 + tid;          // 2048 float4 = 64 x 32
      int r = l4 >> 5, c4 = l4 & 31;
      st4(&Xb[r][c4 * 4], ld4(&X[((size_t)b * 64 + r) * 128 + c4 * 4]));
      st4(&Wx[r][c4 * 4], ld4(&w_a1[(size_t)(256 + r) * 128 + c4 * 4]));
    }
    __syncthreads();
    int dg = tid & 15, kg = tid >> 4;  // kg in [0,32): 4 k-cols each
    float acc[8][4] = {};
    #pragma unroll 4
    for (int tau = 0; tau < 64; ++tau) {
      float4 xa0 = ld4(&Xb[tau][dg * 4]);
      float4 xa1 = ld4(&Xb[tau][64 + dg * 4]);
      float4 wa = ld4(&Wx[tau][kg * 4]);
      #pragma unroll
      for (int i = 0; i < 8; ++i) {
        float xv = (i < 4) ? f4c(xa0, i) : f4c(xa1, i - 4);
        #pragma unroll
        for (int j = 0; j < 4; ++j)
          acc[i][j] = fmaf(xv, f4c(wa, j), acc[i][j]);
      }
    }
    float4 ba = ld4(&b_a1[kg * 4]);
    #pragma unroll
    for (int i = 0; i < 8; ++i) {
      int drow = (i < 4) ? dg * 4 + i : 64 + dg * 4 + (i - 4);
      float al = alpha_g[drow];
      float4 o;
      float* po = &o.x;
      #pragma unroll
      for (int j = 0; j < 4; ++j) {
        float v = 2.0f * fmaf(al, acc[i][j], f4c(ba, j));
        po[j] = __expf(fminf(fmaxf(v, -40.0f), 40.0f));
      }
      st4(&EP[((size_t)b * 128 + drow) * 128 + kg * 4], o);
    }
    return;
  }

  // ---------------- recurrence role ----------------
  unsigned short* kBp = reinterpret_cast<unsigned short*>(shmem);  // kB[2][2048]
  unsigned short* kCp = kBp + 4096;                                // kC[2][2048]
  int wv = tid >> 6, l = tid & 63, lg = l >> 4, lr = l & 15;
  int b0 = bid * 16;

  // A-frags w_hh: ah[ks][q]; j = q*128 + wv*16 + lr; k(m) = ks*32 + lg*8 + e
  bf16x8 ah[4][4];
  #pragma unroll
  for (int ks = 0; ks < 4; ++ks)
    #pragma unroll
    for (int q = 0; q < 4; ++q) {
      const float* src = &w_hh[(size_t)(q * 128 + wv * 16 + lr) * 128 + ks * 32 + lg * 8];
      float4 f0 = ld4(src), f1 = ld4(src + 4);
      bf16x8 fr;
      fr[0] = (__bf16)f0.x; fr[1] = (__bf16)f0.y;
      fr[2] = (__bf16)f0.z; fr[3] = (__bf16)f0.w;
      fr[4] = (__bf16)f1.x; fr[5] = (__bf16)f1.y;
      fr[6] = (__bf16)f1.z; fr[7] = (__bf16)f1.w;
      ah[ks][q] = fr;
    }

  // A-frags w1T (EQ): wt[ks]; n-row = wv*16 + lr; k(m) = ks*32 + lg*8
  bf16x8 wt[8];
  #pragma unroll
  for (int ks = 0; ks < 8; ++ks)
    wt[ks] = *reinterpret_cast<const bf16x8*>(
        &w1T[(size_t)(wv * 16 + lr) * 256 + ks * 32 + lg * 8]);

  alignas(16) float hA[4] = {0.f, 0.f, 0.f, 0.f};
  alignas(16) float cA[4] = {0.f, 0.f, 0.f, 0.f};
  int m0 = wv * 16 + lg * 4;
  int wIdx = lr * 128 + (((m0 >> 3) ^ lr) << 3) + (m0 & 7);  // swizzled write slot
  const __hip_bfloat16* gxb = gx + (size_t)(b0 + lr) * 64 * 512 + wv * 16 + lg * 4;

  // prologue: h(0)=c(0)=0; prefetch gx(0), gx(1)
  uint2 z; z.x = 0u; z.y = 0u;
  *reinterpret_cast<uint2*>(&kBp[wIdx]) = z;
  *reinterpret_cast<uint2*>(&kCp[wIdx]) = z;
  uint2 gA[4], gB[4];
  #pragma unroll
  for (int q = 0; q < 4; ++q) gA[q] = *reinterpret_cast<const uint2*>(gxb + q * 128);
  #pragma unroll
  for (int q = 0; q < 4; ++q) gB[q] = *reinterpret_cast<const uint2*>(gxb + 512 + q * 128);
  __syncthreads();

#define REC_STEP(T, SRC, DST, G)                                               \
  do {                                                                         \
    int t_ = (T);                                                              \
    bf16x8 bh[4], bc[4];                                                       \
    _Pragma("unroll")                                                          \
    for (int ks = 0; ks < 4; ++ks) {                                           \
      int idx_ = lr * 128 + ((((ks << 2) + lg) ^ lr) << 3);                    \
      bh[ks] = *reinterpret_cast<const bf16x8*>(&kBp[(SRC) * 2048 + idx_]);    \
      bc[ks] = *reinterpret_cast<const bf16x8*>(&kCp[(SRC) * 2048 + idx_]);    \
    }                                                                          \
    f32x4 ac0 = cvt4(G[0]), ac1 = cvt4(G[1]), ac2 = cvt4(G[2]), ac3 = cvt4(G[3]); \
    int tn_ = t_ + 2 < 64 ? t_ + 2 : 63;                                       \
    _Pragma("unroll")                                                          \
    for (int q = 0; q < 4; ++q)                                                \
      G[q] = *reinterpret_cast<const uint2*>(gxb + (size_t)tn_ * 512 + q * 128); \
    f32x4 ea = (f32x4){0.f, 0.f, 0.f, 0.f};                                    \
    _Pragma("unroll")                                                          \
    for (int ks = 0; ks < 4; ++ks) {                                           \
      ac0 = __builtin_amdgcn_mfma_f32_16x16x32_bf16(ah[ks][0], bh[ks], ac0, 0, 0, 0); \
      ac1 = __builtin_amdgcn_mfma_f32_16x16x32_bf16(ah[ks][1], bh[ks], ac1, 0, 0, 0); \
      ac2 = __builtin_amdgcn_mfma_f32_16x16x32_bf16(ah[ks][2], bh[ks], ac2, 0, 0, 0); \
      ac3 = __builtin_amdgcn_mfma_f32_16x16x32_bf16(ah[ks][3], bh[ks], ac3, 0, 0, 0); \
    }                                                                          \
    _Pragma("unroll")                                                          \
    for (int ks = 0; ks < 4; ++ks)                                             \
      ea = __builtin_amdgcn_mfma_f32_16x16x32_bf16(wt[ks], bh[ks], ea, 0, 0, 0); \
    _Pragma("unroll")                                                          \
    for (int ks = 0; ks < 4; ++ks)                                             \
      ea = __builtin_amdgcn_mfma_f32_16x16x32_bf16(wt[ks + 4], bc[ks], ea, 0, 0, 0); \
    {                                                                          \
      float4 eo;                                                               \
      float* pe = &eo.x;                                                       \
      _Pragma("unroll")                                                        \
      for (int r = 0; r < 4; ++r) {                                            \
        float v = 2.0f * ea[r];                                                \
        pe[r] = __expf(fminf(fmaxf(v, -40.0f), 40.0f));                        \
      }                                                                        \
      st4(&EQ[((size_t)(t_ * 512) + b0 + lr) * 128 + wv * 16 + lg * 4], eo);   \
    }                                                                          \
    _Pragma("unroll")                                                          \
    for (int r = 0; r < 4; ++r) {                                              \
      float ig = sigmoid_fast(ac0[r]);                                         \
      float fg = sigmoid_fast(ac1[r]);                                         \
      float gg = tanh_fast(ac2[r]);                                            \
      float og = sigmoid_fast(ac3[r]);                                         \
      float cn = fmaf(fg, cA[r], ig * gg);                                     \
      float hn = og * tanh_fast(cn);                                           \
      cA[r] = cn; hA[r] = hn;                                                  \
    }                                                                          \
    {                                                                          \
      uint2 hu; hu.x = pack2(hA[0], hA[1]); hu.y = pack2(hA[2], hA[3]);        \
      uint2 cu; cu.x = pack2(cA[0], cA[1]); cu.y = pack2(cA[2], cA[3]);        \
      *reinterpret_cast<uint2*>(&kBp[(DST) * 2048 + wIdx]) = hu;               \
      *reinterpret_cast<uint2*>(&kCp[(DST) * 2048 + wIdx]) = cu;               \
    }                                                                          \
    barrier_lgkm();                                                            \
  } while (0)

  #pragma unroll 1
  for (int it = 0; it < 32; ++it) {
    REC_STEP(2 * it, 0, 1, gA);
    REC_STEP(2 * it + 1, 1, 0, gB);
  }
#undef REC_STEP
}

// ---------------------------------------------------------------------------
// K_ATTN: per (b): e'[t,d] = -2*sum_k w_a2[k]*rcp(EP[b,d,k]*EQ[t,b,k]+1);
// softmax over d; out[b,t,d] = sm * alpha[d] * X[b,t,d].
// 8 t's per barrier round; plain __syncthreads (round-4 behavior).
// ---------------------------------------------------------------------------
__global__ __launch_bounds__(512, 2) void k_attn(
    const float* __restrict__ EP, const float* __restrict__ EQ,
    const float* __restrict__ w_a2, const float* __restrict__ alpha,
    const float* __restrict__ X, float* __restrict__ out) {
  __shared__ float EQs[64][128];
  __shared__ float e_lds[8][128];
  int b = blockIdx.x;
  int tid = threadIdx.x;
  #pragma unroll
  for (int i = 0; i < 4; ++i) {
    int l4 = i * 512 + tid;
    int t = l4 >> 5, k4 = l4 & 31;
    st4(&EQs[t][k4 * 4], ld4(&EQ[((size_t)t * 512 + b) * 128 + k4 * 4]));
  }
  int d = tid >> 2, s = tid & 3;
  float4 ep[8], w2r[8];
  #pragma unroll
  for (int q = 0; q < 8; ++q) {
    ep[q]  = ld4(&EP[((size_t)b * 128 + d) * 128 + s * 32 + q * 4]);
    w2r[q] = ld4(&w_a2[s * 32 + q * 4]);
  }
  int wv = tid >> 6, l = tid & 63;
  float al0 = alpha[l], al1 = alpha[64 + l];
  __syncthreads();

  for (int rnd = 0; rnd < 8; ++rnd) {
    #pragma unroll
    for (int it = 0; it < 8; ++it) {
      int t = rnd * 8 + it;
      float p = 0.0f;
      #pragma unroll
      for (int q = 0; q < 8; ++q) {
        float4 eq = ld4(&EQs[t][s * 32 + q * 4]);
        p = fmaf(w2r[q].x, fast_rcp(fmaf(ep[q].x, eq.x, 1.0f)), p);
        p = fmaf(w2r[q].y, fast_rcp(fmaf(ep[q].y, eq.y, 1.0f)), p);
        p = fmaf(w2r[q].z, fast_rcp(fmaf(ep[q].z, eq.z, 1.0f)), p);
        p = fmaf(w2r[q].w, fast_rcp(fmaf(ep[q].w, eq.w, 1.0f)), p);
      }
      p += __shfl_xor(p, 1);
      p += __shfl_xor(p, 2);
      if (s == 0) e_lds[it][d] = -2.0f * p;
    }
    __syncthreads();
    {
      int t = rnd * 8 + wv;
      float v0 = e_lds[wv][l], v1 = e_lds[wv][64 + l];
      float mx = fmaxf(v0, v1);
      #pragma unroll
      for (int o = 1; o < 64; o <<= 1) mx = fmaxf(mx, __shfl_xor(mx, o));
      float e0 = __expf(v0 - mx), e1 = __expf(v1 - mx);
      float sm = e0 + e1;
      #pragma unroll
      for (int o = 1; o < 64; o <<= 1) sm += __shfl_xor(sm, o);
      float inv = fast_rcp(sm);
      size_t ro = ((size_t)b * 64 + t) * 128;
      out[ro + l]      = e0 * inv * al0 * X[ro + l];
      out[ro + 64 + l] = e1 * inv * al1 * X[ro + 64 + l];
    }
    __syncthreads();
  }
}

// ---------------------------------------------------------------------------
extern "C" void kernel_launch(void* const* d_in, const int* in_sizes, int n_in,
                              void* d_out, int out_size, void* d_ws, size_t ws_size,
                              hipStream_t stream) {
  const float* X    = (const float*)d_in[0];
  const float* AD   = (const float*)d_in[1];
  const float* W1   = (const float*)d_in[2];
  const float* B1   = (const float*)d_in[3];
  const float* W2   = (const float*)d_in[4];
  const float* B2   = (const float*)d_in[5];
  const float* w_a1 = (const float*)d_in[6];
  const float* b_a1 = (const float*)d_in[7];
  const float* w_a2 = (const float*)d_in[8];
  // d_in[9] = b_a2: softmax-invariant, unused
  const float* w_ih = (const float*)d_in[10];
  const float* w_hh = (const float*)d_in[11];
  const float* b_ih = (const float*)d_in[12];
  const float* b_hh = (const float*)d_in[13];
  float* out = (float*)d_out;
  float* ws = (float*)d_ws;

  // workspace layout (float units)
  float* alpha = ws;                                    // 256
  float* EQ    = ws + 256;                              // 4194304
  float* EP    = EQ + 4194304;                          // 8388608
  float* fgx   = EP + 8388608;                          // gx bf16: 8388608 floats
  __hip_bfloat16* gx = (__hip_bfloat16*)fgx;
  float* fw1T  = fgx + 8388608;                         // w1T bf16: 16384 floats
  __hip_bfloat16* w1T = (__hip_bfloat16*)fw1T;
  float* fwA   = fw1T + 16384;                          // wA bf16: 32768 floats
  __hip_bfloat16* wA = (__hip_bfloat16*)fwA;
  float* biasJ = fwA + 32768;                           // 512
  // total ~= 21.0M floats ~= 84 MB

  hipLaunchKernelGGL(k_prep,  dim3(68),      dim3(256), 0, stream,
                     AD, W1, B1, W2, B2, w_ih, b_ih, b_hh, w_a1,
                     alpha, wA, biasJ, w1T);
  hipLaunchKernelGGL(k_gxw,   dim3(256, 4),  dim3(256), 0, stream, X, wA, biasJ, gx);
  hipLaunchKernelGGL(k_recep, dim3(544),     dim3(512), 0, stream,
                     gx, w_hh, w1T, EQ, X, w_a1, b_a1, alpha, EP);
  hipLaunchKernelGGL(k_attn,  dim3(512),     dim3(512), 0, stream,
                     EP, EQ, w_a2, alpha, X, out);
}

// Round 8
// 321.108 us; speedup vs baseline: 1.1302x; 1.0309x over previous
//
#include <hip/hip_runtime.h>
#include <hip/hip_bf16.h>
#include <cstddef>
#include <cstdint>

// Problem dims (fixed): B=512, T=64, D=128, H=128, FA=64
#define DEVI __device__ __forceinline__

typedef float f32x4 __attribute__((ext_vector_type(4)));
typedef __bf16 bf16x8 __attribute__((ext_vector_type(8)));

DEVI float fast_rcp(float x) { return __builtin_amdgcn_rcpf(x); }
DEVI float sigmoid_fast(float x) { return fast_rcp(1.0f + __expf(-x)); }
DEVI float tanh_fast(float x) { return 1.0f - 2.0f * fast_rcp(__expf(2.0f * x) + 1.0f); }
DEVI float4 ld4(const float* p) { return *reinterpret_cast<const float4*>(p); }
DEVI void st4(float* p, float4 v) { *reinterpret_cast<float4*>(p) = v; }
DEVI float f4c(const float4& v, int i) { return i == 0 ? v.x : i == 1 ? v.y : i == 2 ? v.z : v.w; }
DEVI unsigned short bfbits(float f) { return __builtin_bit_cast(unsigned short, (__bf16)f); }
DEVI unsigned pack2(float a, float b) {
  return (unsigned)bfbits(a) | ((unsigned)bfbits(b) << 16);
}
DEVI f32x4 cvt4(uint2 u) {  // 4 bf16 -> 4 f32 (shift-left-16)
  f32x4 r;
  r[0] = __builtin_bit_cast(float, (u.x & 0xffffu) << 16);
  r[1] = __builtin_bit_cast(float, u.x & 0xffff0000u);
  r[2] = __builtin_bit_cast(float, (u.y & 0xffffu) << 16);
  r[3] = __builtin_bit_cast(float, u.y & 0xffff0000u);
  return r;
}
// Barrier WITHOUT the vmcnt(0) drain __syncthreads would emit (global loads/
// stores stay in flight across it; only LDS ops must be visible).
DEVI void barrier_lgkm() {
  __builtin_amdgcn_sched_barrier(0);
  asm volatile("s_waitcnt lgkmcnt(0)" ::: "memory");
  __builtin_amdgcn_s_barrier();
  __builtin_amdgcn_sched_barrier(0);
}

// ---------------------------------------------------------------------------
// K_PREP: fused {alpha (redundant per wih-block), wA/biasJ, w1T transpose}.
// Blocks 0..63: alpha + wA slice (+ block 0 writes alpha_g, biasJ).
// Blocks 64..67: w_a1[0:256]^T -> w1T bf16.
// ---------------------------------------------------------------------------
__global__ __launch_bounds__(256) void k_prep(
    const float* __restrict__ AD, const float* __restrict__ W1,
    const float* __restrict__ B1, const float* __restrict__ W2,
    const float* __restrict__ B2, const float* __restrict__ w_ih,
    const float* __restrict__ b_ih, const float* __restrict__ b_hh,
    const float* __restrict__ w_a1, float* __restrict__ alpha_g,
    __hip_bfloat16* __restrict__ wA, float* __restrict__ biasJ,
    __hip_bfloat16* __restrict__ w1T) {
  __shared__ float sh[64 * 132];  // 33 KB, carved per role
  int bid = blockIdx.x, tid = threadIdx.x;
  if (bid < 64) {
    float* sW1 = sh;            // 2048
    float* sW2 = sh + 2048;     // 32
    float* sB1 = sh + 2080;     // 32
    float* red = sh + 2112;     // 128
    float* sA  = sh + 2240;     // 128
    float* sMS = sh + 2368;     // 2
    for (int i = tid; i < 2048; i += 256) sW1[i] = W1[i];
    if (tid < 32) { sW2[tid] = W2[tid]; sB1[tid] = B1[tid]; }
    __syncthreads();
    if (tid < 128) {
      float ad[64];
      #pragma unroll
      for (int f = 0; f < 64; ++f) ad[f] = AD[tid * 64 + f];
      float logit = B2[0];
      #pragma unroll
      for (int j = 0; j < 32; ++j) {
        float a = sB1[j];
        #pragma unroll
        for (int f = 0; f < 64; ++f) a = fmaf(ad[f], sW1[f * 32 + j], a);
        a = a > 0.0f ? a : 0.5f * a;  // LeakyReLU(0.5)
        logit = fmaf(a, sW2[j], logit);
      }
      red[tid] = logit;
    }
    __syncthreads();
    if (tid == 0) {
      float mx = red[0];
      for (int i = 1; i < 128; ++i) mx = fmaxf(mx, red[i]);
      float sm = 0.0f;
      for (int i = 0; i < 128; ++i) sm += __expf(red[i] - mx);
      sMS[0] = mx; sMS[1] = sm;
    }
    __syncthreads();
    if (tid < 128) {
      float a = __expf(red[tid] - sMS[0]) / sMS[1];
      sA[tid] = a;
      if (bid == 0) alpha_g[tid] = a;
    }
    __syncthreads();
    // wA slice: 256 quads per block
    int i4 = bid * 256 + tid;
    int j = i4 >> 5, d0 = (i4 & 31) * 4;
    float4 w = ld4(&w_ih[(size_t)j * 128 + d0]);
    uint2 o;
    o.x = pack2(w.x * sA[d0], w.y * sA[d0 + 1]);
    o.y = pack2(w.z * sA[d0 + 2], w.w * sA[d0 + 3]);
    *reinterpret_cast<uint2*>(&wA[(size_t)j * 128 + d0]) = o;
    if (i4 < 128) {
      int jb = i4 * 4;
      float4 v0 = ld4(&b_ih[jb]), v1 = ld4(&b_hh[jb]);
      v0.x += v1.x; v0.y += v1.y; v0.z += v1.z; v0.w += v1.w;
      st4(&biasJ[jb], v0);
    }
  } else {
    // w1T transpose role
    float (*tile)[132] = reinterpret_cast<float(*)[132]>(sh);
    int blk = bid - 64;
    #pragma unroll
    for (int i = 0; i < 32; ++i) {
      int idx = i * 256 + tid;
      int r = idx >> 7, c = idx & 127;
      tile[r][c] = w_a1[(size_t)(blk * 64 + r) * 128 + c];
    }
    __syncthreads();
    int n = tid >> 1, mh = tid & 1;
    unsigned* dst = reinterpret_cast<unsigned*>(&w1T[(size_t)n * 256 + blk * 64 + mh * 32]);
    #pragma unroll
    for (int i = 0; i < 16; ++i) {
      float a = tile[mh * 32 + 2 * i][n];
      float b = tile[mh * 32 + 2 * i + 1][n];
      dst[i] = pack2(a, b);
    }
  }
}

// ---------------------------------------------------------------------------
// K_GXW v2: gx[r=(b*64+t)][j] bf16 = sum_d X[r][d]*wA[j][d] + biasJ[j]
// Grid (4 jt, 256 rt): jt-mates adjacent -> concurrent -> X served from L3.
// Epilogue stages the C tile in LDS and writes gx with coalesced uint4
// stores (fixes 5x write amplification of the scattered 8B/1KB-stride path).
// ---------------------------------------------------------------------------
__global__ __launch_bounds__(256, 2) void k_gxw(
    const float* __restrict__ X, const __hip_bfloat16* __restrict__ wA,
    const float* __restrict__ biasJ, __hip_bfloat16* __restrict__ gx) {
  __shared__ unsigned short tile[128 * 136];  // rows padded to 272B (16B mult)
  int jt = blockIdx.x, rt = blockIdx.y;
  int tid = threadIdx.x;
  int wv = tid >> 6, l = tid & 63, lg = l >> 4, lr = l & 15;
  int r0 = rt * 128;
  int j0 = jt * 128 + wv * 32;

  bf16x8 a[2][4];
  #pragma unroll
  for (int ri = 0; ri < 2; ++ri)
    #pragma unroll
    for (int ks = 0; ks < 4; ++ks)
      a[ri][ks] = *reinterpret_cast<const bf16x8*>(
          &wA[(size_t)(j0 + ri * 16 + lr) * 128 + ks * 32 + lg * 8]);

  f32x4 acc[2][8];
  #pragma unroll
  for (int ri = 0; ri < 2; ++ri)
    #pragma unroll
    for (int nj = 0; nj < 8; ++nj) acc[ri][nj] = (f32x4){0.f, 0.f, 0.f, 0.f};

  #pragma unroll 2
  for (int nj = 0; nj < 8; ++nj) {
    bf16x8 bh[4];
    #pragma unroll
    for (int ks = 0; ks < 4; ++ks) {
      const float* src = &X[(size_t)(r0 + nj * 16 + lr) * 128 + ks * 32 + lg * 8];
      float4 f0 = ld4(src), f1 = ld4(src + 4);
      bf16x8 fr;
      fr[0] = (__bf16)f0.x; fr[1] = (__bf16)f0.y;
      fr[2] = (__bf16)f0.z; fr[3] = (__bf16)f0.w;
      fr[4] = (__bf16)f1.x; fr[5] = (__bf16)f1.y;
      fr[6] = (__bf16)f1.z; fr[7] = (__bf16)f1.w;
      bh[ks] = fr;
    }
    #pragma unroll
    for (int ks = 0; ks < 4; ++ks) {
      acc[0][nj] = __builtin_amdgcn_mfma_f32_16x16x32_bf16(a[0][ks], bh[ks], acc[0][nj], 0, 0, 0);
      acc[1][nj] = __builtin_amdgcn_mfma_f32_16x16x32_bf16(a[1][ks], bh[ks], acc[1][nj], 0, 0, 0);
    }
  }

  // stage C into LDS: row = X-row (nj*16+lr), col = j_local (wv*32+ri*16+lg*4)
  #pragma unroll
  for (int ri = 0; ri < 2; ++ri) {
    int jb = j0 + ri * 16 + lg * 4;
    float4 bi = ld4(&biasJ[jb]);
    int jloc = wv * 32 + ri * 16 + lg * 4;
    #pragma unroll
    for (int nj = 0; nj < 8; ++nj) {
      int row = nj * 16 + lr;
      uint2 o;
      o.x = pack2(acc[ri][nj][0] + bi.x, acc[ri][nj][1] + bi.y);
      o.y = pack2(acc[ri][nj][2] + bi.z, acc[ri][nj][3] + bi.w);
      *reinterpret_cast<uint2*>(&tile[row * 136 + jloc]) = o;
    }
  }
  __syncthreads();

  // coalesced write-out: 128 rows x 256B; each thread 8 x 16B
  #pragma unroll
  for (int i = 0; i < 8; ++i) {
    int idx = i * 256 + tid;            // 0..2047
    int row = idx >> 4, seg = idx & 15;
    uint4 v = *reinterpret_cast<const uint4*>(&tile[row * 136 + seg * 8]);
    *reinterpret_cast<uint4*>(&gx[(size_t)(r0 + row) * 512 + jt * 128 + seg * 8]) = v;
  }
}

// ---------------------------------------------------------------------------
// K_RECEP: blocks 0..31 = LSTM recurrence + fused EQ; blocks 32..543 = EP.
// EQ for step t is emitted AFTER barrier(t), from register copies of the
// h/c frags (pbh/pbc) -> EQ work interleaves with step t+1's ds_read/MFMAs
// and leaves the serial h critical path.
// ---------------------------------------------------------------------------
__global__ __launch_bounds__(512, 1) void k_recep(
    const __hip_bfloat16* __restrict__ gx, const float* __restrict__ w_hh,
    const __hip_bfloat16* __restrict__ w1T, float* __restrict__ EQ,
    const float* __restrict__ X, const float* __restrict__ w_a1,
    const float* __restrict__ b_a1, const float* __restrict__ alpha_g,
    float* __restrict__ EP) {
  __shared__ float shmem[2 * 64 * 128];  // 64 KB
  int bid = blockIdx.x;
  int tid = threadIdx.x;

  if (bid >= 32) {
    // ---------------- EP role ----------------
    int b = bid - 32;
    float (*Xb)[128] = reinterpret_cast<float(*)[128]>(&shmem[0]);
    float (*Wx)[128] = reinterpret_cast<float(*)[128]>(&shmem[8192]);
    #pragma unroll
    for (int i = 0; i < 4; ++i) {
      int l4 = i * 512 + tid;          // 2048 float4 = 64 x 32
      int r = l4 >> 5, c4 = l4 & 31;
      st4(&Xb[r][c4 * 4], ld4(&X[((size_t)b * 64 + r) * 128 + c4 * 4]));
      st4(&Wx[r][c4 * 4], ld4(&w_a1[(size_t)(256 + r) * 128 + c4 * 4]));
    }
    __syncthreads();
    int dg = tid & 15, kg = tid >> 4;  // kg in [0,32): 4 k-cols each
    float acc[8][4] = {};
    #pragma unroll 4
    for (int tau = 0; tau < 64; ++tau) {
      float4 xa0 = ld4(&Xb[tau][dg * 4]);
      float4 xa1 = ld4(&Xb[tau][64 + dg * 4]);
      float4 wa = ld4(&Wx[tau][kg * 4]);
      #pragma unroll
      for (int i = 0; i < 8; ++i) {
        float xv = (i < 4) ? f4c(xa0, i) : f4c(xa1, i - 4);
        #pragma unroll
        for (int j = 0; j < 4; ++j)
          acc[i][j] = fmaf(xv, f4c(wa, j), acc[i][j]);
      }
    }
    float4 ba = ld4(&b_a1[kg * 4]);
    #pragma unroll
    for (int i = 0; i < 8; ++i) {
      int drow = (i < 4) ? dg * 4 + i : 64 + dg * 4 + (i - 4);
      float al = alpha_g[drow];
      float4 o;
      float* po = &o.x;
      #pragma unroll
      for (int j = 0; j < 4; ++j) {
        float v = 2.0f * fmaf(al, acc[i][j], f4c(ba, j));
        po[j] = __expf(fminf(fmaxf(v, -40.0f), 40.0f));
      }
      st4(&EP[((size_t)b * 128 + drow) * 128 + kg * 4], o);
    }
    return;
  }

  // ---------------- recurrence role ----------------
  unsigned short* kBp = reinterpret_cast<unsigned short*>(shmem);  // kB[2][2048]
  unsigned short* kCp = kBp + 4096;                                // kC[2][2048]
  int wv = tid >> 6, l = tid & 63, lg = l >> 4, lr = l & 15;
  int b0 = bid * 16;

  // A-frags w_hh: ah[ks][q]; j = q*128 + wv*16 + lr; k(m) = ks*32 + lg*8 + e
  bf16x8 ah[4][4];
  #pragma unroll
  for (int ks = 0; ks < 4; ++ks)
    #pragma unroll
    for (int q = 0; q < 4; ++q) {
      const float* src = &w_hh[(size_t)(q * 128 + wv * 16 + lr) * 128 + ks * 32 + lg * 8];
      float4 f0 = ld4(src), f1 = ld4(src + 4);
      bf16x8 fr;
      fr[0] = (__bf16)f0.x; fr[1] = (__bf16)f0.y;
      fr[2] = (__bf16)f0.z; fr[3] = (__bf16)f0.w;
      fr[4] = (__bf16)f1.x; fr[5] = (__bf16)f1.y;
      fr[6] = (__bf16)f1.z; fr[7] = (__bf16)f1.w;
      ah[ks][q] = fr;
    }

  // A-frags w1T (EQ): wt[ks]; n-row = wv*16 + lr; k(m) = ks*32 + lg*8
  bf16x8 wt[8];
  #pragma unroll
  for (int ks = 0; ks < 8; ++ks)
    wt[ks] = *reinterpret_cast<const bf16x8*>(
        &w1T[(size_t)(wv * 16 + lr) * 256 + ks * 32 + lg * 8]);

  alignas(16) float hA[4] = {0.f, 0.f, 0.f, 0.f};
  alignas(16) float cA[4] = {0.f, 0.f, 0.f, 0.f};
  int m0 = wv * 16 + lg * 4;
  int wIdx = lr * 128 + (((m0 >> 3) ^ lr) << 3) + (m0 & 7);  // swizzled write slot
  const __hip_bfloat16* gxb = gx + (size_t)(b0 + lr) * 64 * 512 + wv * 16 + lg * 4;

  // prologue: h(0)=c(0)=0; prefetch gx(0), gx(1)
  uint2 z; z.x = 0u; z.y = 0u;
  *reinterpret_cast<uint2*>(&kBp[wIdx]) = z;
  *reinterpret_cast<uint2*>(&kCp[wIdx]) = z;
  uint2 gA[4], gB[4];
  #pragma unroll
  for (int q = 0; q < 4; ++q) gA[q] = *reinterpret_cast<const uint2*>(gxb + q * 128);
  #pragma unroll
  for (int q = 0; q < 4; ++q) gB[q] = *reinterpret_cast<const uint2*>(gxb + 512 + q * 128);
  __syncthreads();

  bf16x8 pbh[4], pbc[4];  // saved h/c frags of the previous step (for EQ)

#define EQ_EMIT(PT)                                                            \
  do {                                                                         \
    f32x4 eh = (f32x4){0.f, 0.f, 0.f, 0.f};                                    \
    f32x4 ec = (f32x4){0.f, 0.f, 0.f, 0.f};                                    \
    _Pragma("unroll")                                                          \
    for (int ks = 0; ks < 4; ++ks) {                                           \
      eh = __builtin_amdgcn_mfma_f32_16x16x32_bf16(wt[ks], pbh[ks], eh, 0, 0, 0); \
      ec = __builtin_amdgcn_mfma_f32_16x16x32_bf16(wt[ks + 4], pbc[ks], ec, 0, 0, 0); \
    }                                                                          \
    float4 eo;                                                                 \
    float* pe = &eo.x;                                                         \
    _Pragma("unroll")                                                          \
    for (int r = 0; r < 4; ++r) {                                              \
      float v = 2.0f * (eh[r] + ec[r]);                                        \
      pe[r] = __expf(fminf(fmaxf(v, -40.0f), 40.0f));                          \
    }                                                                          \
    st4(&EQ[((size_t)((PT) * 512) + b0 + lr) * 128 + wv * 16 + lg * 4], eo);   \
  } while (0)

#define REC_STEP(T, SRC, DST, G, EMIT)                                         \
  do {                                                                         \
    int t_ = (T);                                                              \
    if (EMIT) EQ_EMIT(t_ - 1);                                                 \
    bf16x8 bh[4], bc[4];                                                       \
    _Pragma("unroll")                                                          \
    for (int ks = 0; ks < 4; ++ks) {                                           \
      int idx_ = lr * 128 + ((((ks << 2) + lg) ^ lr) << 3);                    \
      bh[ks] = *reinterpret_cast<const bf16x8*>(&kBp[(SRC) * 2048 + idx_]);    \
      bc[ks] = *reinterpret_cast<const bf16x8*>(&kCp[(SRC) * 2048 + idx_]);    \
    }                                                                          \
    f32x4 ac0 = cvt4(G[0]), ac1 = cvt4(G[1]), ac2 = cvt4(G[2]), ac3 = cvt4(G[3]); \
    int tn_ = t_ + 2 < 64 ? t_ + 2 : 63;                                       \
    _Pragma("unroll")                                                          \
    for (int q = 0; q < 4; ++q)                                                \
      G[q] = *reinterpret_cast<const uint2*>(gxb + (size_t)tn_ * 512 + q * 128); \
    _Pragma("unroll")                                                          \
    for (int ks = 0; ks < 4; ++ks) {                                           \
      ac0 = __builtin_amdgcn_mfma_f32_16x16x32_bf16(ah[ks][0], bh[ks], ac0, 0, 0, 0); \
      ac1 = __builtin_amdgcn_mfma_f32_16x16x32_bf16(ah[ks][1], bh[ks], ac1, 0, 0, 0); \
      ac2 = __builtin_amdgcn_mfma_f32_16x16x32_bf16(ah[ks][2], bh[ks], ac2, 0, 0, 0); \
      ac3 = __builtin_amdgcn_mfma_f32_16x16x32_bf16(ah[ks][3], bh[ks], ac3, 0, 0, 0); \
    }                                                                          \
    _Pragma("unroll")                                                          \
    for (int r = 0; r < 4; ++r) {                                              \
      float ig = sigmoid_fast(ac0[r]);                                         \
      float fg = sigmoid_fast(ac1[r]);                                         \
      float gg = tanh_fast(ac2[r]);                                            \
      float og = sigmoid_fast(ac3[r]);                                         \
      float cn = fmaf(fg, cA[r], ig * gg);                                     \
      float hn = og * tanh_fast(cn);                                           \
      cA[r] = cn; hA[r] = hn;                                                  \
    }                                                                          \
    {                                                                          \
      uint2 hu; hu.x = pack2(hA[0], hA[1]); hu.y = pack2(hA[2], hA[3]);        \
      uint2 cu; cu.x = pack2(cA[0], cA[1]); cu.y = pack2(cA[2], cA[3]);        \
      *reinterpret_cast<uint2*>(&kBp[(DST) * 2048 + wIdx]) = hu;               \
      *reinterpret_cast<uint2*>(&kCp[(DST) * 2048 + wIdx]) = cu;               \
    }                                                                          \
    _Pragma("unroll")                                                          \
    for (int ks = 0; ks < 4; ++ks) { pbh[ks] = bh[ks]; pbc[ks] = bc[ks]; }     \
    barrier_lgkm();                                                            \
  } while (0)

  REC_STEP(0, 0, 1, gA, 0);
  REC_STEP(1, 1, 0, gB, 1);
  #pragma unroll 1
  for (int it = 1; it < 32; ++it) {
    REC_STEP(2 * it, 0, 1, gA, 1);
    REC_STEP(2 * it + 1, 1, 0, gB, 1);
  }
  EQ_EMIT(63);
#undef REC_STEP
#undef EQ_EMIT
}

// ---------------------------------------------------------------------------
// K_ATTN: per (b): e'[t,d] = -2*sum_k w_a2[k]*rcp(EP[b,d,k]*EQ[t,b,k]+1);
// softmax over d; out[b,t,d] = sm * alpha[d] * X[b,t,d].
// 8 t's per barrier round; two independent fma chains (latency split).
// ---------------------------------------------------------------------------
__global__ __launch_bounds__(512, 2) void k_attn(
    const float* __restrict__ EP, const float* __restrict__ EQ,
    const float* __restrict__ w_a2, const float* __restrict__ alpha,
    const float* __restrict__ X, float* __restrict__ out) {
  __shared__ float EQs[64][128];
  __shared__ float e_lds[8][128];
  int b = blockIdx.x;
  int tid = threadIdx.x;
  #pragma unroll
  for (int i = 0; i < 4; ++i) {
    int l4 = i * 512 + tid;
    int t = l4 >> 5, k4 = l4 & 31;
    st4(&EQs[t][k4 * 4], ld4(&EQ[((size_t)t * 512 + b) * 128 + k4 * 4]));
  }
  int d = tid >> 2, s = tid & 3;
  float4 ep[8], w2r[8];
  #pragma unroll
  for (int q = 0; q < 8; ++q) {
    ep[q]  = ld4(&EP[((size_t)b * 128 + d) * 128 + s * 32 + q * 4]);
    w2r[q] = ld4(&w_a2[s * 32 + q * 4]);
  }
  int wv = tid >> 6, l = tid & 63;
  float al0 = alpha[l], al1 = alpha[64 + l];
  __syncthreads();

  for (int rnd = 0; rnd < 8; ++rnd) {
    #pragma unroll
    for (int it = 0; it < 8; ++it) {
      int t = rnd * 8 + it;
      float pa = 0.0f, pb = 0.0f;
      #pragma unroll
      for (int q = 0; q < 4; ++q) {
        float4 eqa = ld4(&EQs[t][s * 32 + q * 4]);
        float4 eqb = ld4(&EQs[t][s * 32 + 16 + q * 4]);
        pa = fmaf(w2r[q].x, fast_rcp(fmaf(ep[q].x, eqa.x, 1.0f)), pa);
        pa = fmaf(w2r[q].y, fast_rcp(fmaf(ep[q].y, eqa.y, 1.0f)), pa);
        pa = fmaf(w2r[q].z, fast_rcp(fmaf(ep[q].z, eqa.z, 1.0f)), pa);
        pa = fmaf(w2r[q].w, fast_rcp(fmaf(ep[q].w, eqa.w, 1.0f)), pa);
        pb = fmaf(w2r[q + 4].x, fast_rcp(fmaf(ep[q + 4].x, eqb.x, 1.0f)), pb);
        pb = fmaf(w2r[q + 4].y, fast_rcp(fmaf(ep[q + 4].y, eqb.y, 1.0f)), pb);
        pb = fmaf(w2r[q + 4].z, fast_rcp(fmaf(ep[q + 4].z, eqb.z, 1.0f)), pb);
        pb = fmaf(w2r[q + 4].w, fast_rcp(fmaf(ep[q + 4].w, eqb.w, 1.0f)), pb);
      }
      float p = pa + pb;
      p += __shfl_xor(p, 1);
      p += __shfl_xor(p, 2);
      if (s == 0) e_lds[it][d] = -2.0f * p;
    }
    __syncthreads();
    {
      int t = rnd * 8 + wv;
      float v0 = e_lds[wv][l], v1 = e_lds[wv][64 + l];
      float mx = fmaxf(v0, v1);
      #pragma unroll
      for (int o = 1; o < 64; o <<= 1) mx = fmaxf(mx, __shfl_xor(mx, o));
      float e0 = __expf(v0 - mx), e1 = __expf(v1 - mx);
      float sm = e0 + e1;
      #pragma unroll
      for (int o = 1; o < 64; o <<= 1) sm += __shfl_xor(sm, o);
      float inv = fast_rcp(sm);
      size_t ro = ((size_t)b * 64 + t) * 128;
      out[ro + l]      = e0 * inv * al0 * X[ro + l];
      out[ro + 64 + l] = e1 * inv * al1 * X[ro + 64 + l];
    }
    __syncthreads();
  }
}

// ---------------------------------------------------------------------------
extern "C" void kernel_launch(void* const* d_in, const int* in_sizes, int n_in,
                              void* d_out, int out_size, void* d_ws, size_t ws_size,
                              hipStream_t stream) {
  const float* X    = (const float*)d_in[0];
  const float* AD   = (const float*)d_in[1];
  const float* W1   = (const float*)d_in[2];
  const float* B1   = (const float*)d_in[3];
  const float* W2   = (const float*)d_in[4];
  const float* B2   = (const float*)d_in[5];
  const float* w_a1 = (const float*)d_in[6];
  const float* b_a1 = (const float*)d_in[7];
  const float* w_a2 = (const float*)d_in[8];
  // d_in[9] = b_a2: softmax-invariant, unused
  const float* w_ih = (const float*)d_in[10];
  const float* w_hh = (const float*)d_in[11];
  const float* b_ih = (const float*)d_in[12];
  const float* b_hh = (const float*)d_in[13];
  float* out = (float*)d_out;
  float* ws = (float*)d_ws;

  // workspace layout (float units)
  float* alpha = ws;                                    // 256
  float* EQ    = ws + 256;                              // 4194304
  float* EP    = EQ + 4194304;                          // 8388608
  float* fgx   = EP + 8388608;                          // gx bf16: 8388608 floats
  __hip_bfloat16* gx = (__hip_bfloat16*)fgx;
  float* fw1T  = fgx + 8388608;                         // w1T bf16: 16384 floats
  __hip_bfloat16* w1T = (__hip_bfloat16*)fw1T;
  float* fwA   = fw1T + 16384;                          // wA bf16: 32768 floats
  __hip_bfloat16* wA = (__hip_bfloat16*)fwA;
  float* biasJ = fwA + 32768;                           // 512
  // total ~= 21.0M floats ~= 84 MB

  hipLaunchKernelGGL(k_prep,  dim3(68),      dim3(256), 0, stream,
                     AD, W1, B1, W2, B2, w_ih, b_ih, b_hh, w_a1,
                     alpha, wA, biasJ, w1T);
  hipLaunchKernelGGL(k_gxw,   dim3(4, 256),  dim3(256), 0, stream, X, wA, biasJ, gx);
  hipLaunchKernelGGL(k_recep, dim3(544),     dim3(512), 0, stream,
                     gx, w_hh, w1T, EQ, X, w_a1, b_a1, alpha, EP);
  hipLaunchKernelGGL(k_attn,  dim3(512),     dim3(512), 0, stream,
                     EP, EQ, w_a2, alpha, X, out);
}